// Round 3
// baseline (249.082 us; speedup 1.0000x reference)
//
#include <hip/hip_runtime.h>
#include <hip/hip_cooperative_groups.h>
#include <math.h>

namespace cg = cooperative_groups;

// Problem constants (setup_inputs: T=16384, J=64, d=1024, all fp32)
#define T_DIM 16384
#define J_DIM 64
#define D_DIM 1024

#define NB   512                  // blocks (2 per CU, coop-co-resident)
#define RPB  32                   // rows of h per block (T / NB)

// Scratch lives INSIDE d_out (float offsets) — no d_ws usage at all.
// It occupies the first ~2.003 MiB of the 64 MiB output and is fully
// overwritten by phase C after the second grid sync.
#define PART_OFF 0                // part[b][dd]: 512 x 1024 floats
#define MB_OFF   (NB * D_DIM)     // 524288: 512 block maxes
#define ZB_OFF   (MB_OFF + NB)    // 524800: 512 block partial denoms

typedef float floatx4 __attribute__((ext_vector_type(4)));  // nontemporal-store-compatible

// ============================================================================
// Fused cooperative kernel.
//  Phase A: block b owns h/s rows [b*32, b*32+32): row-max via 16-lane
//    shuffles, block max Mb + weights, heavy float4 sweep of 32 h-rows with
//    FMA into per-thread float4, partials -> out[]
//  grid.sync()
//  Phase B (2 dims/block): global max M over 512 Mb, sc_b = exp(Mb-M),
//    Z = sum sc_b*Zb, ctx[dd] = sum sc_b*part[b][dd] for dd0=2b, dd1=2b+1;
//    val = ctx/Z held in registers.
//  grid.sync()  (no block may overwrite scratch before all have read it)
//  Phase C: nontemporal vector broadcast of rows dd0, dd1 (64 KiB each).
// ============================================================================
__global__ __launch_bounds__(256) void fused(const float* __restrict__ h,
                                             const float* __restrict__ s,
                                             float* __restrict__ out) {
    __shared__ float rowmax[RPB];
    __shared__ float wts[RPB];
    __shared__ float redm[256];
    __shared__ float redz[256];
    __shared__ float redc0[256];
    __shared__ float redc1[256];

    const int tid = threadIdx.x;
    const int b   = blockIdx.x;

    // --- A1) row maxes over J=64 (16 float4/row; 16 consecutive lanes/row)
    const float4* s4 = (const float4*)s + (size_t)b * (RPB * J_DIM / 4);
    float4 v0 = s4[tid];
    float4 v1 = s4[tid + 256];
    float m0 = fmaxf(fmaxf(v0.x, v0.y), fmaxf(v0.z, v0.w));
    float m1 = fmaxf(fmaxf(v1.x, v1.y), fmaxf(v1.z, v1.w));
#pragma unroll
    for (int off = 1; off < 16; off <<= 1) {
        m0 = fmaxf(m0, __shfl_xor(m0, off));
        m1 = fmaxf(m1, __shfl_xor(m1, off));
    }
    if ((tid & 15) == 0) {
        rowmax[tid >> 4] = m0;            // rows 0..15
        rowmax[16 + (tid >> 4)] = m1;     // rows 16..31
    }
    __syncthreads();

    // --- A2) block max, local weights, local denom (tiny, off BW path)
    if (tid == 0) {
        float Mb = rowmax[0];
#pragma unroll
        for (int r = 1; r < RPB; ++r) Mb = fmaxf(Mb, rowmax[r]);
        float Zb = 0.f;
#pragma unroll
        for (int r = 0; r < RPB; ++r) {
            const float w = expf(rowmax[r] - Mb);
            wts[r] = w;
            Zb += w;
        }
        out[MB_OFF + b] = Mb;
        out[ZB_OFF + b] = Zb;
    }
    __syncthreads();

    // --- A3) heavy pass: 32 rows x 1024 floats, perfectly coalesced
    const float4* h4 = (const float4*)h;
    float4 acc = make_float4(0.f, 0.f, 0.f, 0.f);
    const size_t base = (size_t)b * (RPB * D_DIM / 4) + tid;
#pragma unroll 8
    for (int r = 0; r < RPB; ++r) {
        const float4 v = h4[base + (size_t)r * (D_DIM / 4)];
        const float wt = wts[r];
        acc.x = fmaf(wt, v.x, acc.x);
        acc.y = fmaf(wt, v.y, acc.y);
        acc.z = fmaf(wt, v.z, acc.z);
        acc.w = fmaf(wt, v.w, acc.w);
    }
    ((float4*)(out + PART_OFF))[(size_t)b * (D_DIM / 4) + tid] = acc;

    cg::this_grid().sync();   // partials/Mb/Zb visible device-wide

    // --- B) global reduce; this block produces dims dd0=2b, dd1=2b+1
    const int dd0 = 2 * b;
    const int dd1 = 2 * b + 1;
    const float bm0 = out[MB_OFF + tid];
    const float bm1 = out[MB_OFF + tid + 256];
    // issue part loads early (independent of the max reduction)
    const float* prow = out + PART_OFF + (size_t)tid * D_DIM;
    const float p00 = prow[dd0];
    const float p01 = prow[dd1];
    const float p10 = prow[(size_t)256 * D_DIM + dd0];
    const float p11 = prow[(size_t)256 * D_DIM + dd1];
    const float bz0 = out[ZB_OFF + tid];
    const float bz1 = out[ZB_OFF + tid + 256];

    redm[tid] = fmaxf(bm0, bm1);
    __syncthreads();
#pragma unroll
    for (int off = 128; off > 0; off >>= 1) {
        if (tid < off) redm[tid] = fmaxf(redm[tid], redm[tid + off]);
        __syncthreads();
    }
    const float M = redm[0];

    const float sc0 = expf(bm0 - M);
    const float sc1 = expf(bm1 - M);
    redz[tid]  = sc0 * bz0 + sc1 * bz1;
    redc0[tid] = sc0 * p00 + sc1 * p10;
    redc1[tid] = sc0 * p01 + sc1 * p11;
    __syncthreads();
#pragma unroll
    for (int off = 128; off > 0; off >>= 1) {
        if (tid < off) {
            redz[tid]  += redz[tid + off];
            redc0[tid] += redc0[tid + off];
            redc1[tid] += redc1[tid + off];
        }
        __syncthreads();
    }
    const float val0 = redc0[0] / redz[0];
    const float val1 = redc1[0] / redz[0];

    cg::this_grid().sync();   // all scratch reads done before any overwrite

    // --- C) broadcast rows dd0, dd1 (64 KiB each), nontemporal vector stores
    const floatx4 w0 = { val0, val0, val0, val0 };
    const floatx4 w1 = { val1, val1, val1, val1 };
    floatx4* o0 = (floatx4*)out + (size_t)dd0 * (T_DIM / 4);
    floatx4* o1 = (floatx4*)out + (size_t)dd1 * (T_DIM / 4);
#pragma unroll
    for (int i = 0; i < T_DIM / 4 / 256; ++i) {   // 16 vector stores per row
        __builtin_nontemporal_store(w0, o0 + (size_t)i * 256 + tid);
        __builtin_nontemporal_store(w1, o1 + (size_t)i * 256 + tid);
    }
}

extern "C" void kernel_launch(void* const* d_in, const int* in_sizes, int n_in,
                              void* d_out, int out_size, void* d_ws, size_t ws_size,
                              hipStream_t stream) {
    const float* h = (const float*)d_in[0];   // (1, T, d) fp32
    const float* s = (const float*)d_in[1];   // (T, J) fp32
    float* out = (float*)d_out;               // (d, T) fp32
    // d_ws intentionally untouched: its 256 MiB per-iteration fill was the
    // dominant cost in the timed graph.
    void* args[] = { (void*)&h, (void*)&s, (void*)&out };
    (void)hipLaunchCooperativeKernel((const void*)fused, dim3(NB), dim3(256),
                                     args, 0, stream);
}

// Round 4
// 125.478 us; speedup vs baseline: 1.9851x; 1.9851x over previous
//
#include <hip/hip_runtime.h>
#include <math.h>

// Problem constants (setup_inputs: T=16384, J=64, d=1024, all fp32)
#define T_DIM 16384
#define J_DIM 64
#define D_DIM 1024

#define NB   1024                 // heavy-pass blocks (4 per CU, 16 waves/CU)
#define RPB  16                   // rows of h per block (T / NB)

// ws layout (float offsets). No zero-init required anywhere (no atomics).
#define MB_OFF   0                // 1024 block maxes
#define ZB_OFF   1024             // 1024 block partial softmax denoms
#define PART_OFF 2048             // part[b][dd]: 1024 x 1024 floats, 16B aligned

typedef float floatx4 __attribute__((ext_vector_type(4)));  // nontemporal-builtin-compatible

// ============================================================================
// kb: fused softmax-weights + heavy weighted-sum pass.
// Block b owns rows [b*16, b*16+16).
//   1) 16 s-rows (4 KB, coalesced float4; 16 consecutive lanes/row), row-max
//      via 16-lane shuffle butterflies,
//   2) thread 0: block max Mb, weights w[r]=exp(m[r]-Mb), Zb=sum w  (tiny),
//   3) heavy pass: 256 threads sweep one 4 KB h-row/iter as coalesced
//      nontemporal float4 loads (read-once: keep out of L2/L3), FMA into
//      per-thread float4 acc,
//   4) write partial ctx (coalesced float4) + Mb, Zb.
// ============================================================================
__global__ __launch_bounds__(256) void kb_heavy(const float* __restrict__ h,
                                                const float* __restrict__ s,
                                                float* __restrict__ ws) {
    __shared__ float rowmax[RPB];
    __shared__ float wts[RPB];
    const int tid = threadIdx.x;
    const int b = blockIdx.x;

    // --- 1) row maxes over J=64 (16 float4 per row; 16 consecutive lanes/row)
    const float4* s4 = (const float4*)s + (size_t)b * (RPB * J_DIM / 4); // 256 f4/block
    const float4 v0 = s4[tid];
    float m0 = fmaxf(fmaxf(v0.x, v0.y), fmaxf(v0.z, v0.w));
#pragma unroll
    for (int off = 1; off < 16; off <<= 1)
        m0 = fmaxf(m0, __shfl_xor(m0, off));
    if ((tid & 15) == 0) rowmax[tid >> 4] = m0;   // rows 0..15
    __syncthreads();

    // --- 2) block max, local weights, local denom (serial: 16 iters, off BW path)
    if (tid == 0) {
        float Mb = rowmax[0];
#pragma unroll
        for (int r = 1; r < RPB; ++r) Mb = fmaxf(Mb, rowmax[r]);
        float Zb = 0.f;
#pragma unroll
        for (int r = 0; r < RPB; ++r) {
            const float w = expf(rowmax[r] - Mb);
            wts[r] = w;
            Zb += w;
        }
        ws[MB_OFF + b] = Mb;
        ws[ZB_OFF + b] = Zb;
    }
    __syncthreads();

    // --- 3) heavy pass: 16 rows x 1024 floats, perfectly coalesced, nt loads
    const floatx4* h4 = (const floatx4*)h;
    floatx4 acc = {0.f, 0.f, 0.f, 0.f};
    const size_t base = (size_t)b * (RPB * D_DIM / 4) + tid;
#pragma unroll 8
    for (int r = 0; r < RPB; ++r) {
        const floatx4 v = __builtin_nontemporal_load(h4 + base + (size_t)r * (D_DIM / 4));
        const float wt = wts[r];
        acc[0] = fmaf(wt, v[0], acc[0]);
        acc[1] = fmaf(wt, v[1], acc[1]);
        acc[2] = fmaf(wt, v[2], acc[2]);
        acc[3] = fmaf(wt, v[3], acc[3]);
    }

    // --- 4) partial ctx, coalesced float4 store: part[b][4tid..4tid+3]
    ((floatx4*)(ws + PART_OFF))[(size_t)b * (D_DIM / 4) + tid] = acc;
}

// ============================================================================
// kcd: fused rescale-reduce + broadcast. One block per output dim dd.
//   M = max_b Mb (LDS reduce), sc_b = exp(Mb-M),
//   Z = sum sc_b*Zb, ctx = sum sc_b*part[b][dd]   (part reads strided but
//   L2/L3-resident: 4 MB with 16-way line reuse), then stream the 64 KB
//   output row out[dd][0..T) = ctx/Z as nontemporal float4 stores.
// ============================================================================
__global__ __launch_bounds__(256) void kcd_reduce_bcast(const float* __restrict__ ws,
                                                        floatx4* __restrict__ out4) {
    __shared__ float redm[256];
    __shared__ float redz[256];
    __shared__ float redc[256];
    const int tid = threadIdx.x;
    const int dd = blockIdx.x;

    float m[4], z[4], p[4];
#pragma unroll
    for (int k = 0; k < 4; ++k) {
        const int bb = tid + 256 * k;
        m[k] = ws[MB_OFF + bb];
        // issue part loads early (independent of the max reduction)
        p[k] = ws[PART_OFF + (size_t)bb * D_DIM + dd];
        z[k] = ws[ZB_OFF + bb];
    }

    redm[tid] = fmaxf(fmaxf(m[0], m[1]), fmaxf(m[2], m[3]));
    __syncthreads();
#pragma unroll
    for (int off = 128; off > 0; off >>= 1) {
        if (tid < off) redm[tid] = fmaxf(redm[tid], redm[tid + off]);
        __syncthreads();
    }
    const float M = redm[0];

    float zz = 0.f, cc = 0.f;
#pragma unroll
    for (int k = 0; k < 4; ++k) {
        const float sc = expf(m[k] - M);
        zz = fmaf(sc, z[k], zz);
        cc = fmaf(sc, p[k], cc);
    }
    redz[tid] = zz;
    redc[tid] = cc;
    __syncthreads();
#pragma unroll
    for (int off = 128; off > 0; off >>= 1) {
        if (tid < off) {
            redz[tid] += redz[tid + off];
            redc[tid] += redc[tid + off];
        }
        __syncthreads();
    }
    const float val = redc[0] / redz[0];

    const floatx4 v4 = {val, val, val, val};
    floatx4* o = out4 + (size_t)dd * (T_DIM / 4);
#pragma unroll
    for (int i = 0; i < T_DIM / 4 / 256; ++i)   // 16 float4 stores per thread
        __builtin_nontemporal_store(v4, o + (size_t)i * 256 + tid);
}

extern "C" void kernel_launch(void* const* d_in, const int* in_sizes, int n_in,
                              void* d_out, int out_size, void* d_ws, size_t ws_size,
                              hipStream_t stream) {
    const float* h = (const float*)d_in[0];   // (1, T, d) fp32
    const float* s = (const float*)d_in[1];   // (T, J) fp32
    float* ws = (float*)d_ws;
    floatx4* out = (floatx4*)d_out;           // (d, T) fp32

    kb_heavy<<<NB, 256, 0, stream>>>(h, s, ws);
    kcd_reduce_bcast<<<D_DIM, 256, 0, stream>>>(ws, out);
}